// Round 1
// baseline (487.963 us; speedup 1.0000x reference)
//
#include <hip/hip_runtime.h>
#include <cstdint>
#include <cstddef>

#define EMBED 768
#define NHEAD 32
#define HDIM 24
#define BATCH 4
#define SEQ 512
#define WCOLS 1632      // 768 q | 768 k | 96 vw
#define WSTRIDE 1664    // padded to multiple of 128
#define GBM 64
#define GBN 128
#define GBK 16

static __device__ __constant__ float kScaling = 0.20412414523193154f; // 24^-0.5

// ---------------------------------------------------------------------------
// prep: build W_cat (768 x 1664) = [Wq^T*s | Wk^T | Wv^T@Wf_head | 0pad],
// b_cat likewise. Row e==768 of the grid handles the bias vector.
// ---------------------------------------------------------------------------
__global__ __launch_bounds__(128) void prep_kernel(
    const float* __restrict__ Wq, const float* __restrict__ bq,
    const float* __restrict__ Wk, const float* __restrict__ bk,
    const float* __restrict__ Wv, const float* __restrict__ bv,
    const float* __restrict__ Wf,
    float* __restrict__ Wcat, float* __restrict__ bcat)
{
    int j = blockIdx.x * 128 + threadIdx.x;
    int e = blockIdx.y;
    if (j >= WSTRIDE) return;
    if (e < EMBED) {
        float v;
        if (j < 768) {
            v = Wq[(size_t)j * EMBED + e] * kScaling;
        } else if (j < 1536) {
            v = Wk[(size_t)(j - 768) * EMBED + e];
        } else if (j < WCOLS) {
            int jc = j - 1536; int h = jc / 3; int c = jc - h * 3;
            float s = 0.f;
            #pragma unroll
            for (int d = 0; d < HDIM; ++d)
                s = fmaf(Wv[(size_t)(h * HDIM + d) * EMBED + e],
                         Wf[c * EMBED + h * HDIM + d], s);
            v = s;
        } else {
            v = 0.f;
        }
        Wcat[(size_t)e * WSTRIDE + j] = v;
    } else {
        float v;
        if (j < 768) {
            v = bq[j] * kScaling;
        } else if (j < 1536) {
            v = bk[j - 768];
        } else if (j < WCOLS) {
            int jc = j - 1536; int h = jc / 3; int c = jc - h * 3;
            float s = 0.f;
            #pragma unroll
            for (int d = 0; d < HDIM; ++d)
                s = fmaf(bv[h * HDIM + d], Wf[c * EMBED + h * HDIM + d], s);
            v = s;
        } else {
            v = 0.f;
        }
        bcat[j] = v;
    }
}

// ---------------------------------------------------------------------------
// GEMM: C[2048][1664] = query[2048][768] @ Wcat[768][1664] (+bias), epilogue
// scatters into q[b][h][n][d] (pre-scaled), k[b][h][m][d], vw[b][h][c][m].
// f32 vector-pipe GEMM, 64x128 tile, 256 threads, 4x8 per thread.
// ---------------------------------------------------------------------------
__global__ __launch_bounds__(256) void gemm_kernel(
    const float* __restrict__ A, const float* __restrict__ Wc,
    const float* __restrict__ bc,
    float* __restrict__ qb, float* __restrict__ kb, float* __restrict__ vwb)
{
    __shared__ float As[GBK][GBM + 4];   // transposed store, padded
    __shared__ float Bs[GBK][GBN];
    int tid = threadIdx.x;
    int r0 = blockIdx.x * GBM;
    int j0 = blockIdx.y * GBN;
    int tm0 = (tid >> 4) * 4;       // 0..60
    int tn0 = (tid & 15) * 8;       // 0..120

    float acc[4][8];
    #pragma unroll
    for (int i = 0; i < 4; ++i)
        #pragma unroll
        for (int jj = 0; jj < 8; ++jj) acc[i][jj] = 0.f;

    int lm = tid >> 2;            // 0..63
    int lk = (tid & 3) * 4;       // 0,4,8,12
    int br = tid >> 5;            // 0..7
    int bj = (tid & 31) * 4;      // 0..124

    for (int k0 = 0; k0 < EMBED; k0 += GBK) {
        float4 av = *(const float4*)&A[(size_t)(r0 + lm) * EMBED + k0 + lk];
        float4 w0 = *(const float4*)&Wc[(size_t)(k0 + br) * WSTRIDE + j0 + bj];
        float4 w1 = *(const float4*)&Wc[(size_t)(k0 + br + 8) * WSTRIDE + j0 + bj];
        __syncthreads();   // previous tile's readers done
        As[lk + 0][lm] = av.x; As[lk + 1][lm] = av.y;
        As[lk + 2][lm] = av.z; As[lk + 3][lm] = av.w;
        *(float4*)&Bs[br][bj] = w0;
        *(float4*)&Bs[br + 8][bj] = w1;
        __syncthreads();
        #pragma unroll
        for (int k = 0; k < GBK; ++k) {
            float4 a0 = *(const float4*)&As[k][tm0];
            float4 b0 = *(const float4*)&Bs[k][tn0];
            float4 b1 = *(const float4*)&Bs[k][tn0 + 4];
            float am[4] = {a0.x, a0.y, a0.z, a0.w};
            float bn_[8] = {b0.x, b0.y, b0.z, b0.w, b1.x, b1.y, b1.z, b1.w};
            #pragma unroll
            for (int i = 0; i < 4; ++i)
                #pragma unroll
                for (int jj = 0; jj < 8; ++jj)
                    acc[i][jj] = fmaf(am[i], bn_[jj], acc[i][jj]);
        }
    }

    #pragma unroll
    for (int i = 0; i < 4; ++i) {
        int r = r0 + tm0 + i;
        int b = r >> 9;
        int n = r & 511;
        #pragma unroll
        for (int jj = 0; jj < 8; ++jj) {
            int j = j0 + tn0 + jj;
            if (j >= WCOLS) continue;
            float v = acc[i][jj] + bc[j];
            if (j < 768) {
                int h = j / 24, d = j - h * 24;
                qb[((size_t)((b * NHEAD + h) * SEQ + n)) * HDIM + d] = v;
            } else if (j < 1536) {
                int j2 = j - 768; int h = j2 / 24, d = j2 - h * 24;
                kb[((size_t)((b * NHEAD + h) * SEQ + n)) * HDIM + d] = v;
            } else {
                int jc = j - 1536; int h = jc / 3, c = jc - h * 3;
                vwb[((size_t)((b * NHEAD + h) * 3 + c)) * SEQ + n] = v;
            }
        }
    }
}

// ---------------------------------------------------------------------------
// Fused attention + force.  Block = (b, 8 query rows), 512 threads, t <-> m.
// Per h: k-row in regs (global, dense), q wave-uniform (s_load), bias/vw
// streamed, softmax via wave+LDS reduce, weighted accumulate against
// LDS-staged delta_pos.  2-deep manual h-pipeline to hide VMEM latency.
// ---------------------------------------------------------------------------
struct HBuf { float k[HDIM]; float bs[8]; float vw[3]; };

__device__ __forceinline__ void load_h(HBuf& B, int b, int h, int n0, int t,
    const float* __restrict__ kb, const float* __restrict__ bias,
    const float* __restrict__ vwb)
{
    const float* kr = kb + ((size_t)((b * NHEAD + h) * SEQ) + t) * HDIM;
    #pragma unroll
    for (int c4 = 0; c4 < 6; ++c4) {
        float4 v = *(const float4*)&kr[c4 * 4];
        B.k[c4 * 4 + 0] = v.x; B.k[c4 * 4 + 1] = v.y;
        B.k[c4 * 4 + 2] = v.z; B.k[c4 * 4 + 3] = v.w;
    }
    const float* brow = bias + ((size_t)(b * NHEAD + h) * SEQ + n0) * SEQ + t;
    #pragma unroll
    for (int i = 0; i < 8; ++i) B.bs[i] = brow[(size_t)i * SEQ];
    #pragma unroll
    for (int c = 0; c < 3; ++c)
        B.vw[c] = vwb[((size_t)((b * NHEAD + h) * 3 + c)) * SEQ + t];
}

template <int PH>
__device__ __forceinline__ void compute_h(const HBuf& B, int b, int h, int n0,
    int t, const float* __restrict__ qb, float (&fac)[8][3],
    const float (&delta_s)[8][SEQ][3],
    float (&redm)[2][8][8], float (&reds)[2][8][8])
{
    float s[8];
    const float* qbase = qb + (size_t)((b * NHEAD + h) * SEQ + n0) * HDIM;
    #pragma unroll
    for (int i = 0; i < 8; ++i) {
        float sv = B.bs[i];
        #pragma unroll
        for (int d = 0; d < HDIM; ++d)
            sv = fmaf(qbase[i * HDIM + d], B.k[d], sv);  // q is wave-uniform
        s[i] = sv;
    }
    int w = t >> 6, lane = t & 63;
    float mx[8];
    #pragma unroll
    for (int i = 0; i < 8; ++i) {
        float v = s[i];
        #pragma unroll
        for (int o = 32; o > 0; o >>= 1) v = fmaxf(v, __shfl_xor(v, o));
        mx[i] = v;
    }
    if (lane == 0) {
        #pragma unroll
        for (int i = 0; i < 8; ++i) redm[PH][i][w] = mx[i];
    }
    __syncthreads();
    float e[8], ws[8];
    #pragma unroll
    for (int i = 0; i < 8; ++i) {
        float g = redm[PH][i][0];
        #pragma unroll
        for (int ww = 1; ww < 8; ++ww) g = fmaxf(g, redm[PH][i][ww]);
        e[i] = __expf(s[i] - g);
        float v = e[i];
        #pragma unroll
        for (int o = 32; o > 0; o >>= 1) v += __shfl_xor(v, o);
        ws[i] = v;
    }
    if (lane == 0) {
        #pragma unroll
        for (int i = 0; i < 8; ++i) reds[PH][i][w] = ws[i];
    }
    __syncthreads();
    #pragma unroll
    for (int i = 0; i < 8; ++i) {
        float g = reds[PH][i][0];
        #pragma unroll
        for (int ww = 1; ww < 8; ++ww) g += reds[PH][i][ww];
        float p = e[i] * __builtin_amdgcn_rcpf(g);
        float p0 = p * B.vw[0], p1 = p * B.vw[1], p2 = p * B.vw[2];
        fac[i][0] = fmaf(p0, delta_s[i][t][0], fac[i][0]);
        fac[i][1] = fmaf(p1, delta_s[i][t][1], fac[i][1]);
        fac[i][2] = fmaf(p2, delta_s[i][t][2], fac[i][2]);
    }
}

__global__ __launch_bounds__(512) void attn_kernel(
    const float* __restrict__ qb, const float* __restrict__ kb,
    const float* __restrict__ vwb, const float* __restrict__ bias,
    const float* __restrict__ delta, const float* __restrict__ bf,
    float* __restrict__ out)
{
    __shared__ float delta_s[8][SEQ][3];      // 48 KiB
    __shared__ float redm[2][8][8];
    __shared__ float reds[2][8][8];
    __shared__ float wred[8][8][3];
    int t = threadIdx.x;
    int b = blockIdx.x >> 6;
    int n0 = (blockIdx.x & 63) * 8;

    {   // stage delta_pos rows n0..n0+7 (contiguous, float4, coalesced)
        const float4* src = (const float4*)(delta + (size_t)(b * SEQ + n0) * SEQ * 3);
        float4* dst = (float4*)&delta_s[0][0][0];
        #pragma unroll
        for (int it = 0; it < 6; ++it) dst[t + it * 512] = src[t + it * 512];
    }
    float fac[8][3];
    #pragma unroll
    for (int i = 0; i < 8; ++i) { fac[i][0] = 0.f; fac[i][1] = 0.f; fac[i][2] = 0.f; }
    __syncthreads();

    HBuf A, Bb;
    load_h(A, b, 0, n0, t, kb, bias, vwb);
    for (int h = 0; h < NHEAD; h += 2) {
        load_h(Bb, b, h + 1, n0, t, kb, bias, vwb);
        compute_h<0>(A, b, h, n0, t, qb, fac, delta_s, redm, reds);
        if (h + 2 < NHEAD) load_h(A, b, h + 2, n0, t, kb, bias, vwb);
        compute_h<1>(Bb, b, h + 1, n0, t, qb, fac, delta_s, redm, reds);
    }

    int w = t >> 6, lane = t & 63;
    #pragma unroll
    for (int i = 0; i < 8; ++i)
        #pragma unroll
        for (int c = 0; c < 3; ++c) {
            float v = fac[i][c];
            #pragma unroll
            for (int o = 32; o > 0; o >>= 1) v += __shfl_xor(v, o);
            if (lane == 0) wred[w][i][c] = v;
        }
    __syncthreads();
    if (t < 24) {
        int i = t / 3, c = t - i * 3;
        float sm = 0.f;
        #pragma unroll
        for (int ww = 0; ww < 8; ++ww) sm += wred[ww][i][c];
        out[(size_t)(b * SEQ + n0 + i) * 3 + c] = sm + bf[c];
    }
}

// ---------------------------------------------------------------------------
extern "C" void kernel_launch(void* const* d_in, const int* in_sizes, int n_in,
                              void* d_out, int out_size, void* d_ws, size_t ws_size,
                              hipStream_t stream)
{
    const float* query = (const float*)d_in[0];
    const float* attn_bias = (const float*)d_in[1];
    const float* delta = (const float*)d_in[2];
    const float* Wq = (const float*)d_in[3];
    const float* bq = (const float*)d_in[4];
    const float* Wk = (const float*)d_in[5];
    const float* bk = (const float*)d_in[6];
    const float* Wv = (const float*)d_in[7];
    const float* bv = (const float*)d_in[8];
    const float* Wf = (const float*)d_in[9];
    const float* bf = (const float*)d_in[10];
    float* out = (float*)d_out;

    float* ws = (float*)d_ws;
    float* qb   = ws;                                  // 4*32*512*24
    float* kb   = qb + (size_t)BATCH * NHEAD * SEQ * HDIM;
    float* vwb  = kb + (size_t)BATCH * NHEAD * SEQ * HDIM;   // 4*32*3*512
    float* Wcat = vwb + (size_t)BATCH * NHEAD * 3 * SEQ;     // 768*1664
    float* bcat = Wcat + (size_t)EMBED * WSTRIDE;            // 1664

    hipLaunchKernelGGL(prep_kernel, dim3(13, EMBED + 1), dim3(128), 0, stream,
                       Wq, bq, Wk, bk, Wv, bv, Wf, Wcat, bcat);
    hipLaunchKernelGGL(gemm_kernel, dim3((BATCH * SEQ) / GBM, WSTRIDE / GBN),
                       dim3(256), 0, stream, query, Wcat, bcat, qb, kb, vwb);
    hipLaunchKernelGGL(attn_kernel, dim3(BATCH * (SEQ / 8)), dim3(512), 0, stream,
                       qb, kb, vwb, attn_bias, delta, bf, out);
}

// Round 2
// 453.677 us; speedup vs baseline: 1.0756x; 1.0756x over previous
//
#include <hip/hip_runtime.h>
#include <cstdint>
#include <cstddef>

#define EMBED 768
#define NHEAD 32
#define HDIM 24
#define BATCH 4
#define SEQ 512
#define WCOLS 1632      // 768 q | 768 k | 96 vw
#define WSTRIDE 1664    // padded to multiple of 64

static __device__ __constant__ float kScaling = 0.20412414523193154f; // 24^-0.5

// ---------------------------------------------------------------------------
// prep: build W_cat (768 x 1664) = [Wq^T*s | Wk^T | Wv^T@Wf_head | 0pad],
// b_cat likewise. Row e==768 of the grid handles the bias vector.
// ---------------------------------------------------------------------------
__global__ __launch_bounds__(128) void prep_kernel(
    const float* __restrict__ Wq, const float* __restrict__ bq,
    const float* __restrict__ Wk, const float* __restrict__ bk,
    const float* __restrict__ Wv, const float* __restrict__ bv,
    const float* __restrict__ Wf,
    float* __restrict__ Wcat, float* __restrict__ bcat)
{
    int j = blockIdx.x * 128 + threadIdx.x;
    int e = blockIdx.y;
    if (j >= WSTRIDE) return;
    if (e < EMBED) {
        float v;
        if (j < 768) {
            v = Wq[(size_t)j * EMBED + e] * kScaling;
        } else if (j < 1536) {
            v = Wk[(size_t)(j - 768) * EMBED + e];
        } else if (j < WCOLS) {
            int jc = j - 1536; int h = jc / 3; int c = jc - h * 3;
            float s = 0.f;
            #pragma unroll
            for (int d = 0; d < HDIM; ++d)
                s = fmaf(Wv[(size_t)(h * HDIM + d) * EMBED + e],
                         Wf[c * EMBED + h * HDIM + d], s);
            v = s;
        } else {
            v = 0.f;
        }
        Wcat[(size_t)e * WSTRIDE + j] = v;
    } else {
        float v;
        if (j < 768) {
            v = bq[j] * kScaling;
        } else if (j < 1536) {
            v = bk[j - 768];
        } else if (j < WCOLS) {
            int jc = j - 1536; int h = jc / 3; int c = jc - h * 3;
            float s = 0.f;
            #pragma unroll
            for (int d = 0; d < HDIM; ++d)
                s = fmaf(bv[h * HDIM + d], Wf[c * EMBED + h * HDIM + d], s);
            v = s;
        } else {
            v = 0.f;
        }
        bcat[j] = v;
    }
}

// ---------------------------------------------------------------------------
// GEMM v2: C[2048][1664] = query[2048][768] @ Wcat (+bias).
// 128x64 tile, 256 threads, 8x4 per thread, GBK=16, double-buffered LDS,
// ONE barrier per K-tile. Grid 16x26 = 416 blocks (~6 resident blocks/CU).
// Epilogue scatters into q[b][h][n][d] (pre-scaled), k[b][h][m][d],
// vw[b][h][c][m].
// ---------------------------------------------------------------------------
#define TBM 128
#define TBN 64
#define TBK 16
#define NKT (EMBED / TBK)   // 48

__global__ __launch_bounds__(256) void gemm_kernel(
    const float* __restrict__ A, const float* __restrict__ Wc,
    const float* __restrict__ bc,
    float* __restrict__ qb, float* __restrict__ kb, float* __restrict__ vwb)
{
    __shared__ float As[2][TBK][TBM + 4];   // [k][m] transposed, padded row=132
    __shared__ float Bs[2][TBK][TBN];
    int tid = threadIdx.x;
    int r0 = blockIdx.x * TBM;
    int j0 = blockIdx.y * TBN;
    int tm = (tid >> 4) * 8;      // 0..120
    int tn = (tid & 15) * 4;      // 0..60

    // staging coords
    int ar = tid >> 2;            // 0..63
    int ak = (tid & 3) * 4;       // 0,4,8,12
    int bk = tid >> 4;            // 0..15
    int bj = (tid & 15) * 4;      // 0..60

    float acc[8][4];
    #pragma unroll
    for (int i = 0; i < 8; ++i)
        #pragma unroll
        for (int jj = 0; jj < 4; ++jj) acc[i][jj] = 0.f;

    const float* Ap0 = A + (size_t)(r0 + ar) * EMBED + ak;
    const float* Ap1 = A + (size_t)(r0 + ar + 64) * EMBED + ak;
    const float* Bp  = Wc + (size_t)bk * WSTRIDE + j0 + bj;

    // prologue: stage tile 0 into buf 0
    {
        float4 a0 = *(const float4*)Ap0;
        float4 a1 = *(const float4*)Ap1;
        float4 b  = *(const float4*)Bp;
        #pragma unroll
        for (int jj = 0; jj < 4; ++jj) {
            As[0][ak + jj][ar]      = ((const float*)&a0)[jj];
            As[0][ak + jj][ar + 64] = ((const float*)&a1)[jj];
        }
        *(float4*)&Bs[0][bk][bj] = b;
    }

    for (int kt = 0; kt < NKT; ++kt) {
        int cur = kt & 1;
        __syncthreads();           // buf[cur] staged & prev readers done
        float4 pa0, pa1, pb;
        bool more = (kt + 1 < NKT);
        if (more) {
            int k1 = (kt + 1) * TBK;
            pa0 = *(const float4*)(Ap0 + k1);
            pa1 = *(const float4*)(Ap1 + k1);
            pb  = *(const float4*)(Bp + (size_t)k1 * WSTRIDE);
        }
        #pragma unroll
        for (int k = 0; k < TBK; ++k) {
            float4 a0 = *(const float4*)&As[cur][k][tm];
            float4 a1 = *(const float4*)&As[cur][k][tm + 4];
            float4 b  = *(const float4*)&Bs[cur][k][tn];
            float am[8] = {a0.x, a0.y, a0.z, a0.w, a1.x, a1.y, a1.z, a1.w};
            float bn_[4] = {b.x, b.y, b.z, b.w};
            #pragma unroll
            for (int i = 0; i < 8; ++i)
                #pragma unroll
                for (int jj = 0; jj < 4; ++jj)
                    acc[i][jj] = fmaf(am[i], bn_[jj], acc[i][jj]);
        }
        if (more) {
            int nxt = cur ^ 1;
            #pragma unroll
            for (int jj = 0; jj < 4; ++jj) {
                As[nxt][ak + jj][ar]      = ((const float*)&pa0)[jj];
                As[nxt][ak + jj][ar + 64] = ((const float*)&pa1)[jj];
            }
            *(float4*)&Bs[nxt][bk][bj] = pb;
        }
    }

    #pragma unroll
    for (int i = 0; i < 8; ++i) {
        int r = r0 + tm + i;
        int b = r >> 9;
        int n = r & 511;
        #pragma unroll
        for (int jj = 0; jj < 4; ++jj) {
            int j = j0 + tn + jj;
            if (j >= WCOLS) continue;
            float v = acc[i][jj] + bc[j];
            if (j < 768) {
                int h = j / 24, d = j - h * 24;
                qb[((size_t)((b * NHEAD + h) * SEQ + n)) * HDIM + d] = v;
            } else if (j < 1536) {
                int j2 = j - 768; int h = j2 / 24, d = j2 - h * 24;
                kb[((size_t)((b * NHEAD + h) * SEQ + n)) * HDIM + d] = v;
            } else {
                int jc = j - 1536; int h = jc / 3, c = jc - h * 3;
                vwb[((size_t)((b * NHEAD + h) * 3 + c)) * SEQ + n] = v;
            }
        }
    }
}

// ---------------------------------------------------------------------------
// init_out: out[b,n,c] = bf[c]; force_kernel atomically adds partials on top.
// ---------------------------------------------------------------------------
__global__ __launch_bounds__(256) void init_out_kernel(
    const float* __restrict__ bf, float* __restrict__ out)
{
    int i = blockIdx.x * 256 + threadIdx.x;
    if (i < BATCH * SEQ * 3) {
        int c = i - (i / 3) * 3;
        out[i] = bf[c];
    }
}

// ---------------------------------------------------------------------------
// denom: Sinv[b,h,n] = 1 / sum_m exp(q.k + bias).  No max-subtraction:
// |score| <= ~8 (bias ~N(0,1) dominates), exp(8)=3e3 is safe in f32.
// Block = (b, h, quarter of n). threads <-> m, k-row cached in regs across
// all 128 rows. 8-row batches, ONE barrier per batch (double-buffered LDS).
// ---------------------------------------------------------------------------
__global__ __launch_bounds__(512) void denom_kernel(
    const float* __restrict__ qb, const float* __restrict__ kb,
    const float* __restrict__ bias, float* __restrict__ Sinv)
{
    __shared__ float part[2][8][8];
    int t = threadIdx.x;
    int b = blockIdx.x, h = blockIdx.y, qq = blockIdx.z;
    int bh = b * NHEAD + h;
    int w = t >> 6, lane = t & 63;

    float kr[HDIM];
    {
        const float* kp = kb + ((size_t)bh * SEQ + t) * HDIM;
        #pragma unroll
        for (int c4 = 0; c4 < 6; ++c4) {
            float4 v = *(const float4*)&kp[c4 * 4];
            kr[c4 * 4 + 0] = v.x; kr[c4 * 4 + 1] = v.y;
            kr[c4 * 4 + 2] = v.z; kr[c4 * 4 + 3] = v.w;
        }
    }

    for (int nb = 0; nb < 16; ++nb) {
        int n = qq * 128 + nb * 8;
        const float* qrow = qb + (size_t)(bh * SEQ + n) * HDIM;  // wave-uniform
        const float* brow = bias + ((size_t)bh * SEQ + n) * SEQ + t;
        float ev[8];
        #pragma unroll
        for (int i = 0; i < 8; ++i) {
            float s = brow[(size_t)i * SEQ];
            #pragma unroll
            for (int d = 0; d < HDIM; ++d)
                s = fmaf(qrow[i * HDIM + d], kr[d], s);
            ev[i] = __expf(s);
        }
        int buf = nb & 1;
        #pragma unroll
        for (int i = 0; i < 8; ++i) {
            float v = ev[i];
            #pragma unroll
            for (int o = 32; o > 0; o >>= 1) v += __shfl_xor(v, o);
            if (lane == 0) part[buf][i][w] = v;
        }
        __syncthreads();
        if (t < 8) {
            float sm = 0.f;
            #pragma unroll
            for (int ww = 0; ww < 8; ++ww) sm += part[buf][t][ww];
            Sinv[(size_t)bh * SEQ + n + t] = 1.0f / sm;
        }
    }
}

// ---------------------------------------------------------------------------
// force: barrier-free main loop. Block = (8 rows n0.., b, headgroup of 8).
// threads <-> m. delta_pos in 24 regs; per head: k-row regs, scores via
// wave-uniform q (s_load), p = exp(s)*Sinv, accumulate pvw[i][c] += p*vw[c].
// Epilogue: fac = pvw*delta, cross-lane+cross-wave reduce, atomicAdd.
// ---------------------------------------------------------------------------
__global__ __launch_bounds__(512) void force_kernel(
    const float* __restrict__ qb, const float* __restrict__ kb,
    const float* __restrict__ vwb, const float* __restrict__ bias,
    const float* __restrict__ delta, const float* __restrict__ Sinv,
    float* __restrict__ out)
{
    __shared__ float wred[8][24];
    int t = threadIdx.x;
    int n0 = blockIdx.x * 8;
    int b = blockIdx.y;
    int hg = blockIdx.z;

    float dl[8][3];
    #pragma unroll
    for (int i = 0; i < 8; ++i) {
        const float* dp = delta + ((size_t)(b * SEQ + n0 + i) * SEQ + t) * 3;
        dl[i][0] = dp[0]; dl[i][1] = dp[1]; dl[i][2] = dp[2];
    }
    float pvw[8][3];
    #pragma unroll
    for (int i = 0; i < 8; ++i) { pvw[i][0] = 0.f; pvw[i][1] = 0.f; pvw[i][2] = 0.f; }

    for (int hh = 0; hh < 8; ++hh) {
        int h = hg * 8 + hh;
        int bh = b * NHEAD + h;
        float kr[HDIM];
        {
            const float* kp = kb + ((size_t)bh * SEQ + t) * HDIM;
            #pragma unroll
            for (int c4 = 0; c4 < 6; ++c4) {
                float4 v = *(const float4*)&kp[c4 * 4];
                kr[c4 * 4 + 0] = v.x; kr[c4 * 4 + 1] = v.y;
                kr[c4 * 4 + 2] = v.z; kr[c4 * 4 + 3] = v.w;
            }
        }
        float vw0 = vwb[((size_t)(bh * 3 + 0)) * SEQ + t];
        float vw1 = vwb[((size_t)(bh * 3 + 1)) * SEQ + t];
        float vw2 = vwb[((size_t)(bh * 3 + 2)) * SEQ + t];
        const float* qrow = qb + (size_t)(bh * SEQ + n0) * HDIM;   // uniform
        const float* brow = bias + ((size_t)bh * SEQ + n0) * SEQ + t;
        const float* sv = Sinv + (size_t)bh * SEQ + n0;            // uniform
        #pragma unroll
        for (int i = 0; i < 8; ++i) {
            float s = brow[(size_t)i * SEQ];
            #pragma unroll
            for (int d = 0; d < HDIM; ++d)
                s = fmaf(qrow[i * HDIM + d], kr[d], s);
            float p = __expf(s) * sv[i];
            pvw[i][0] = fmaf(p, vw0, pvw[i][0]);
            pvw[i][1] = fmaf(p, vw1, pvw[i][1]);
            pvw[i][2] = fmaf(p, vw2, pvw[i][2]);
        }
    }

    int w = t >> 6, lane = t & 63;
    #pragma unroll
    for (int i = 0; i < 8; ++i)
        #pragma unroll
        for (int c = 0; c < 3; ++c) {
            float v = pvw[i][c] * dl[i][c];
            #pragma unroll
            for (int o = 32; o > 0; o >>= 1) v += __shfl_xor(v, o);
            if (lane == 0) wred[w][i * 3 + c] = v;
        }
    __syncthreads();
    if (t < 24) {
        float sm = 0.f;
        #pragma unroll
        for (int ww = 0; ww < 8; ++ww) sm += wred[ww][t];
        atomicAdd(&out[(size_t)(b * SEQ + n0) * 3 + t], sm);
    }
}

// ---------------------------------------------------------------------------
extern "C" void kernel_launch(void* const* d_in, const int* in_sizes, int n_in,
                              void* d_out, int out_size, void* d_ws, size_t ws_size,
                              hipStream_t stream)
{
    const float* query = (const float*)d_in[0];
    const float* attn_bias = (const float*)d_in[1];
    const float* delta = (const float*)d_in[2];
    const float* Wq = (const float*)d_in[3];
    const float* bq = (const float*)d_in[4];
    const float* Wk = (const float*)d_in[5];
    const float* bk = (const float*)d_in[6];
    const float* Wv = (const float*)d_in[7];
    const float* bv = (const float*)d_in[8];
    const float* Wf = (const float*)d_in[9];
    const float* bf = (const float*)d_in[10];
    float* out = (float*)d_out;

    float* ws = (float*)d_ws;
    float* qb   = ws;                                        // 4*32*512*24
    float* kb   = qb + (size_t)BATCH * NHEAD * SEQ * HDIM;
    float* vwb  = kb + (size_t)BATCH * NHEAD * SEQ * HDIM;   // 4*32*3*512
    float* Wcat = vwb + (size_t)BATCH * NHEAD * 3 * SEQ;     // 768*1664
    float* bcat = Wcat + (size_t)EMBED * WSTRIDE;            // 1664
    float* Sinv = bcat + WSTRIDE;                            // 4*32*512

    hipLaunchKernelGGL(prep_kernel, dim3(13, EMBED + 1), dim3(128), 0, stream,
                       Wq, bq, Wk, bk, Wv, bv, Wf, Wcat, bcat);
    hipLaunchKernelGGL(gemm_kernel, dim3((BATCH * SEQ) / TBM, WSTRIDE / TBN),
                       dim3(256), 0, stream, query, Wcat, bcat, qb, kb, vwb);
    hipLaunchKernelGGL(init_out_kernel, dim3((BATCH * SEQ * 3 + 255) / 256),
                       dim3(256), 0, stream, bf, out);
    hipLaunchKernelGGL(denom_kernel, dim3(BATCH, NHEAD, 4), dim3(512), 0, stream,
                       qb, kb, attn_bias, Sinv);
    hipLaunchKernelGGL(force_kernel, dim3(SEQ / 8, BATCH, 4), dim3(512), 0, stream,
                       qb, kb, vwb, attn_bias, delta, Sinv, out);
}

// Round 3
// 259.746 us; speedup vs baseline: 1.8786x; 1.7466x over previous
//
#include <hip/hip_runtime.h>
#include <hip/hip_bf16.h>
#include <cstdint>
#include <cstddef>

#define EMBED 768
#define NHEAD 32
#define HDIM 24
#define DPAD 32          // padded head dim = MFMA K
#define BATCH 4
#define SEQ 512
#define WCOLS 1632       // 768 q | 768 k | 96 vw
#define NPADCOL 1664     // padded to 26*64

typedef __attribute__((ext_vector_type(8))) short short8;
typedef __attribute__((ext_vector_type(4))) short short4v;
typedef __attribute__((ext_vector_type(4))) float f32x4;

static __device__ __forceinline__ unsigned short f2b(float v) {
    __hip_bfloat16 h = __float2bfloat16(v);
    return *reinterpret_cast<unsigned short*>(&h);
}

// ---------------------------------------------------------------------------
// prep_w: WcT[j][e] (bf16, 1664x768) = row j of the fused output matrix:
//   j<768: Wq[j][e]*scal | j<1536: Wk[j-768][e] | j<1632: (Wv^T@Wf)[j] | 0
// Reads and writes both coalesced along e.
// ---------------------------------------------------------------------------
__global__ __launch_bounds__(256) void prep_w_kernel(
    const float* __restrict__ Wq, const float* __restrict__ Wk,
    const float* __restrict__ Wv, const float* __restrict__ Wf,
    unsigned short* __restrict__ WcT)
{
    const float sc = 0.20412414523193154f;  // 24^-0.5
    int j = blockIdx.x;
    #pragma unroll
    for (int rep = 0; rep < 3; ++rep) {
        int e = rep * 256 + threadIdx.x;
        float v;
        if (j < 768) {
            v = Wq[(size_t)j * EMBED + e] * sc;
        } else if (j < 1536) {
            v = Wk[(size_t)(j - 768) * EMBED + e];
        } else if (j < WCOLS) {
            int jc = j - 1536, h = jc / 3, c = jc - h * 3;
            float s = 0.f;
            #pragma unroll
            for (int d = 0; d < HDIM; ++d)
                s = fmaf(Wv[(size_t)(h * HDIM + d) * EMBED + e],
                         Wf[c * EMBED + h * HDIM + d], s);
            v = s;
        } else {
            v = 0.f;
        }
        WcT[(size_t)j * EMBED + e] = f2b(v);
    }
}

__global__ __launch_bounds__(256) void prep_b_kernel(
    const float* __restrict__ bq, const float* __restrict__ bk,
    const float* __restrict__ bv, const float* __restrict__ Wf,
    float* __restrict__ bcat)
{
    int j = blockIdx.x * 256 + threadIdx.x;
    if (j >= NPADCOL) return;
    float v = 0.f;
    if (j < 768) v = bq[j] * 0.20412414523193154f;
    else if (j < 1536) v = bk[j - 768];
    else if (j < WCOLS) {
        int jc = j - 1536, h = jc / 3, c = jc - h * 3;
        float s = 0.f;
        #pragma unroll
        for (int d = 0; d < HDIM; ++d)
            s = fmaf(bv[h * HDIM + d], Wf[c * EMBED + h * HDIM + d], s);
        v = s;
    }
    bcat[j] = v;
}

// query f32 -> bf16 (row-major 2048x768)
__global__ __launch_bounds__(256) void qconv_kernel(
    const float* __restrict__ q, unsigned short* __restrict__ o)
{
    size_t i = ((size_t)blockIdx.x * 256 + threadIdx.x) * 8;
    float4 a = *(const float4*)(q + i);
    float4 b = *(const float4*)(q + i + 4);
    union { unsigned short u[8]; short8 v; } r;
    r.u[0] = f2b(a.x); r.u[1] = f2b(a.y); r.u[2] = f2b(a.z); r.u[3] = f2b(a.w);
    r.u[4] = f2b(b.x); r.u[5] = f2b(b.y); r.u[6] = f2b(b.z); r.u[7] = f2b(b.w);
    *(short8*)(o + i) = r.v;
}

// ---------------------------------------------------------------------------
// MFMA GEMM: C[2048][1664] = queryBf16[2048][768] @ WcT^T (+bcat).
// 64x64 tile, 256 thr (4 waves, 2x2), BK=32, 24 k-iters, 2 barriers/iter.
// LDS rows padded to 36 shorts (72B): conflict-free ds b64 frag reads.
// Epilogue scatters: qp/kp bf16 [bh][n][32] (d<24), vwb f32 [bh][c][m].
// ---------------------------------------------------------------------------
#define LSTR 36
__global__ __launch_bounds__(256) void gemm_kernel(
    const unsigned short* __restrict__ Aq, const unsigned short* __restrict__ WcT,
    const float* __restrict__ bcat,
    unsigned short* __restrict__ qp, unsigned short* __restrict__ kp,
    float* __restrict__ vwb)
{
    __shared__ short As[64 * LSTR];
    __shared__ short Bs[64 * LSTR];
    int t = threadIdx.x;
    int lane = t & 63, wv = t >> 6;
    int l15 = lane & 15, lg = lane >> 4;
    int m0 = blockIdx.x * 64, n0 = blockIdx.y * 64;
    int wm = (wv >> 1) * 32, wn = (wv & 1) * 32;

    f32x4 acc[2][2];
    #pragma unroll
    for (int i = 0; i < 2; ++i)
        #pragma unroll
        for (int j = 0; j < 2; ++j) acc[i][j] = (f32x4){0.f, 0.f, 0.f, 0.f};

    const unsigned short* Ag = Aq + (size_t)(m0 + (t >> 2)) * EMBED + (t & 3) * 8;
    const unsigned short* Bg = WcT + (size_t)(n0 + (t >> 2)) * EMBED + (t & 3) * 8;
    int lidx = (t >> 2) * LSTR + (t & 3) * 8;

    for (int kt = 0; kt < EMBED / 32; ++kt) {
        short8 av = *(const short8*)(Ag + kt * 32);
        short8 bv = *(const short8*)(Bg + kt * 32);
        __syncthreads();   // previous tile's readers done
        union { short4v h[2]; short8 v; } ua, ub;
        ua.v = av; ub.v = bv;
        *(short4v*)&As[lidx] = ua.h[0]; *(short4v*)&As[lidx + 4] = ua.h[1];
        *(short4v*)&Bs[lidx] = ub.h[0]; *(short4v*)&Bs[lidx + 4] = ub.h[1];
        __syncthreads();
        short8 af[2], bfr[2];
        #pragma unroll
        for (int i = 0; i < 2; ++i) {
            int ra = (wm + i * 16 + l15) * LSTR + lg * 8;
            int rb = (wn + i * 16 + l15) * LSTR + lg * 8;
            union { short4v h[2]; short8 v; } u1, u2;
            u1.h[0] = *(const short4v*)&As[ra]; u1.h[1] = *(const short4v*)&As[ra + 4];
            u2.h[0] = *(const short4v*)&Bs[rb]; u2.h[1] = *(const short4v*)&Bs[rb + 4];
            af[i] = u1.v; bfr[i] = u2.v;
        }
        #pragma unroll
        for (int mt = 0; mt < 2; ++mt)
            #pragma unroll
            for (int nt = 0; nt < 2; ++nt)
                acc[mt][nt] = __builtin_amdgcn_mfma_f32_16x16x32_bf16(
                    af[mt], bfr[nt], acc[mt][nt], 0, 0, 0);
    }

    #pragma unroll
    for (int mt = 0; mt < 2; ++mt) {
        #pragma unroll
        for (int nt = 0; nt < 2; ++nt) {
            #pragma unroll
            for (int r = 0; r < 4; ++r) {
                int gm = m0 + wm + mt * 16 + lg * 4 + r;   // token row
                int gn = n0 + wn + nt * 16 + l15;          // output col
                float v = acc[mt][nt][r] + bcat[gn];
                int b = gm >> 9, ns = gm & 511;
                if (gn < 768) {
                    int h = gn / 24, d = gn - h * 24;
                    qp[((size_t)(b * NHEAD + h) * SEQ + ns) * DPAD + d] = f2b(v);
                } else if (gn < 1536) {
                    int j2 = gn - 768, h = j2 / 24, d = j2 - h * 24;
                    kp[((size_t)(b * NHEAD + h) * SEQ + ns) * DPAD + d] = f2b(v);
                } else if (gn < WCOLS) {
                    int jc = gn - 1536, h = jc / 3, c = jc - h * 3;
                    vwb[((size_t)(b * NHEAD + h) * 3 + c) * SEQ + ns] = v;
                }
            }
        }
    }
}

__global__ __launch_bounds__(256) void init_out_kernel(
    const float* __restrict__ bf, float* __restrict__ out)
{
    int i = blockIdx.x * 256 + threadIdx.x;
    if (i < BATCH * SEQ * 3) out[i] = bf[i - (i / 3) * 3];
}

// ---------------------------------------------------------------------------
// Fused attention+force. Block = (16 q-rows, b, 8-head group), 512 thr.
// Wave w owns m-strip [w*64, w*64+64). Per head:
//   S-tile = mfma(Q-frag, K^T-frag) x4  -> D: n=(lane>>4)*4+r, m=lane&15+16*tl
//   e = exp(S + bias)  (no max-sub: |s| <= ~8)
//   den: 4x shfl_xor + LDS cross-wave (1 barrier, double-buffered)
//   fac[r][c] += e*rden * vw[c][m] * delta[n][m][c]   (delta in 48 regs, loaded once)
// Epilogue: shfl + LDS reduce, atomicAdd into out (init'd with bf).
// ---------------------------------------------------------------------------
__global__ __launch_bounds__(512, 4) void attn_kernel(
    const unsigned short* __restrict__ qp, const unsigned short* __restrict__ kp,
    const float* __restrict__ vwb, const float* __restrict__ bias,
    const float* __restrict__ delta, float* __restrict__ out)
{
    __shared__ float denp[2][8][16];
    __shared__ float facp[8][16][3];
    int t = threadIdx.x, lane = t & 63, w = t >> 6;
    int l15 = lane & 15, lg = lane >> 4;
    int nbase = blockIdx.x * 16;
    int b = blockIdx.y;
    int hg = blockIdx.z;
    int mbase = w * 64;

    // delta_pos registers: [r][tile][c], fixed across heads
    float dreg[4][4][3];
    #pragma unroll
    for (int r = 0; r < 4; ++r)
        #pragma unroll
        for (int tl = 0; tl < 4; ++tl) {
            const float* dp = delta +
                ((size_t)(b * SEQ + nbase + lg * 4 + r) * SEQ + mbase + tl * 16 + l15) * 3;
            dreg[r][tl][0] = dp[0]; dreg[r][tl][1] = dp[1]; dreg[r][tl][2] = dp[2];
        }

    float fac[4][3];
    #pragma unroll
    for (int r = 0; r < 4; ++r) { fac[r][0] = 0.f; fac[r][1] = 0.f; fac[r][2] = 0.f; }

    for (int hh = 0; hh < 8; ++hh) {
        int bh = b * NHEAD + hg * 8 + hh;
        short8 aq = *(const short8*)(qp + ((size_t)bh * SEQ + nbase + l15) * DPAD + lg * 8);
        f32x4 acc[4];
        #pragma unroll
        for (int tl = 0; tl < 4; ++tl) {
            short8 bk = *(const short8*)(kp +
                ((size_t)bh * SEQ + mbase + tl * 16 + l15) * DPAD + lg * 8);
            f32x4 z = {0.f, 0.f, 0.f, 0.f};
            acc[tl] = __builtin_amdgcn_mfma_f32_16x16x32_bf16(aq, bk, z, 0, 0, 0);
        }
        float ep[4][4];     // [tile][r]
        float dpart[4] = {0.f, 0.f, 0.f, 0.f};
        #pragma unroll
        for (int tl = 0; tl < 4; ++tl)
            #pragma unroll
            for (int r = 0; r < 4; ++r) {
                float s = acc[tl][r] + bias[
                    ((size_t)bh * SEQ + nbase + lg * 4 + r) * SEQ + mbase + tl * 16 + l15];
                float e = __expf(s);
                ep[tl][r] = e;
                dpart[r] += e;
            }
        #pragma unroll
        for (int r = 0; r < 4; ++r)
            #pragma unroll
            for (int o = 1; o <= 8; o <<= 1)
                dpart[r] += __shfl_xor(dpart[r], o);
        int buf = hh & 1;
        if (l15 == 0) {
            #pragma unroll
            for (int r = 0; r < 4; ++r) denp[buf][w][lg * 4 + r] = dpart[r];
        }
        __syncthreads();
        float rden[4];
        #pragma unroll
        for (int r = 0; r < 4; ++r) {
            float s = 0.f;
            #pragma unroll
            for (int ww = 0; ww < 8; ++ww) s += denp[buf][ww][lg * 4 + r];
            rden[r] = __builtin_amdgcn_rcpf(s);
        }
        #pragma unroll
        for (int tl = 0; tl < 4; ++tl) {
            #pragma unroll
            for (int c = 0; c < 3; ++c) {
                float vv = vwb[((size_t)bh * 3 + c) * SEQ + mbase + tl * 16 + l15];
                #pragma unroll
                for (int r = 0; r < 4; ++r)
                    fac[r][c] = fmaf(ep[tl][r] * rden[r] * vv, dreg[r][tl][c], fac[r][c]);
            }
        }
    }

    #pragma unroll
    for (int r = 0; r < 4; ++r)
        #pragma unroll
        for (int c = 0; c < 3; ++c) {
            float v = fac[r][c];
            #pragma unroll
            for (int o = 1; o <= 8; o <<= 1) v += __shfl_xor(v, o);
            fac[r][c] = v;
        }
    if (l15 == 0) {
        #pragma unroll
        for (int r = 0; r < 4; ++r)
            #pragma unroll
            for (int c = 0; c < 3; ++c) facp[w][lg * 4 + r][c] = fac[r][c];
    }
    __syncthreads();
    if (t < 48) {
        int n = t / 3, c = t - (t / 3) * 3;
        float s = 0.f;
        #pragma unroll
        for (int ww = 0; ww < 8; ++ww) s += facp[ww][n][c];
        atomicAdd(&out[(size_t)(b * SEQ + nbase + n) * 3 + c], s);
    }
}

// ---------------------------------------------------------------------------
extern "C" void kernel_launch(void* const* d_in, const int* in_sizes, int n_in,
                              void* d_out, int out_size, void* d_ws, size_t ws_size,
                              hipStream_t stream)
{
    const float* query = (const float*)d_in[0];
    const float* attn_bias = (const float*)d_in[1];
    const float* delta = (const float*)d_in[2];
    const float* Wq = (const float*)d_in[3];
    const float* bq = (const float*)d_in[4];
    const float* Wk = (const float*)d_in[5];
    const float* bk = (const float*)d_in[6];
    const float* Wv = (const float*)d_in[7];
    const float* bv = (const float*)d_in[8];
    const float* Wf = (const float*)d_in[9];
    const float* bf = (const float*)d_in[10];
    float* out = (float*)d_out;

    uint8_t* p = (uint8_t*)d_ws;
    unsigned short* qp   = (unsigned short*)p; p += (size_t)BATCH * NHEAD * SEQ * DPAD * 2;
    unsigned short* kp   = (unsigned short*)p; p += (size_t)BATCH * NHEAD * SEQ * DPAD * 2;
    unsigned short* qb16 = (unsigned short*)p; p += (size_t)BATCH * SEQ * EMBED * 2;
    unsigned short* WcT  = (unsigned short*)p; p += (size_t)NPADCOL * EMBED * 2;
    float* bcat = (float*)p;                   p += (size_t)NPADCOL * 4;
    float* vwb  = (float*)p;                   p += (size_t)BATCH * NHEAD * 3 * SEQ * 4;

    // zero q/k pads (d=24..31) — epilogue writes only d<24
    hipMemsetAsync(qp, 0, (size_t)BATCH * NHEAD * SEQ * DPAD * 2 * 2, stream);

    hipLaunchKernelGGL(prep_w_kernel, dim3(NPADCOL), dim3(256), 0, stream,
                       Wq, Wk, Wv, Wf, WcT);
    hipLaunchKernelGGL(prep_b_kernel, dim3(7), dim3(256), 0, stream,
                       bq, bk, bv, Wf, bcat);
    hipLaunchKernelGGL(qconv_kernel, dim3((BATCH * SEQ * EMBED) / (256 * 8)),
                       dim3(256), 0, stream, query, qb16);
    hipLaunchKernelGGL(gemm_kernel, dim3((BATCH * SEQ) / 64, NPADCOL / 64),
                       dim3(256), 0, stream, qb16, WcT, bcat, qp, kp, vwb);
    hipLaunchKernelGGL(init_out_kernel, dim3((BATCH * SEQ * 3 + 255) / 256),
                       dim3(256), 0, stream, bf, out);
    hipLaunchKernelGGL(attn_kernel, dim3(SEQ / 16, BATCH, 4), dim3(512), 0, stream,
                       qp, kp, vwb, attn_bias, delta, out);
}